// Round 2
// baseline (310.271 us; speedup 1.0000x reference)
//
#include <hip/hip_runtime.h>
#include <math.h>
#include <stdint.h>

typedef __attribute__((ext_vector_type(8))) _Float16 f16x8;
typedef __attribute__((ext_vector_type(4))) float f32x4;

static __device__ __forceinline__ unsigned short f2h(float f) {
  union { _Float16 h; unsigned short u; } v; v.h = (_Float16)f;
  return v.u;
}
static __device__ __forceinline__ float h2f(unsigned short u) {
  union { unsigned short u; _Float16 h; } v; v.u = u;
  return (float)v.h;
}

// ---------------- pack weights: W2 = [[Wr,-Wi],[Wi,Wr]] (1024x1024 f16), bias2 = br∓bi ----------------
__global__ __launch_bounds__(256) void pack_w(
    const float* __restrict__ Wr, const float* __restrict__ Wi,
    const float* __restrict__ br, const float* __restrict__ bi,
    unsigned short* __restrict__ W2, float* __restrict__ bias2) {
  int idx = blockIdx.x * 256 + threadIdx.x;
  int m = idx >> 10, k = idx & 1023;
  int o = m & 511, d = k & 511;
  float v;
  if (m < 512) v = (k < 512) ? Wr[o * 512 + d] : -Wi[o * 512 + d];
  else         v = (k < 512) ? Wi[o * 512 + d] :  Wr[o * 512 + d];
  W2[idx] = f2h(v);
  if (idx < 1024) {
    int oo = idx & 511;
    bias2[idx] = (idx < 512) ? (br[oo] - bi[oo]) : (br[oo] + bi[oo]);
  }
}

// ---------------- pack x: (B,D,2,S) f32 -> XT[(b*2048+s)][(c*512+d)] f16 (B^T layout) ----------------
__global__ __launch_bounds__(256) void pack_x(
    const float* __restrict__ x, unsigned short* __restrict__ XT) {
  __shared__ unsigned short tl[64][72];
  const int t = threadIdx.x;
  const int sBase = blockIdx.x * 64, dBase = blockIdx.y * 64;
  const int b = blockIdx.z >> 1, c = blockIdx.z & 1;
  const int r = t >> 2, cb = (t & 3) * 16;
  const float* src = x + (((size_t)(b * 512 + dBase + r) * 2 + c) * 2048 + sBase + cb);
#pragma unroll
  for (int j = 0; j < 16; j += 4) {
    float4 v = *(const float4*)(src + j);
    tl[cb + j + 0][r] = f2h(v.x);
    tl[cb + j + 1][r] = f2h(v.y);
    tl[cb + j + 2][r] = f2h(v.z);
    tl[cb + j + 3][r] = f2h(v.w);
  }
  __syncthreads();
  const int s = t >> 2, dc = (t & 3) * 16;
  unsigned short* dst = XT + ((size_t)(b * 2048 + sBase + s)) * 1024 + c * 512 + dBase + dc;
  *(uint4*)dst = *(const uint4*)&tl[s][dc];
  *(uint4*)(dst + 8) = *(const uint4*)&tl[s][dc + 8];
}

// ---------------- GEMM: C[1024][8192] = A(1024x1024) * Bt(8192x1024)^T, f16 in, fp32 acc ----------------
// MODE 0: f16 out channel-major (+bias), z selects weight set / out slab.
// MODE 1: fp32 out scattered to (B,D,2,S) layout of d_out (+bias).
template <int MODE>
__global__ __launch_bounds__(256) void gemm_bt(
    const unsigned short* __restrict__ A, const unsigned short* __restrict__ Bt,
    const float* __restrict__ bias, unsigned short* __restrict__ Cb,
    float* __restrict__ Cf) {
  __shared__ unsigned short As[128][40];
  __shared__ unsigned short Bs[128][40];
  const int t = threadIdx.x;
  const int wave = t >> 6, lane = t & 63;
  const int wr = wave >> 1, wc = wave & 1;
  const int mBase = blockIdx.y * 128, nBase = blockIdx.x * 128;
  const int z = blockIdx.z;
  A += (size_t)z * 1024 * 1024;
  bias += z * 1024;
  if (MODE == 0) Cb += (size_t)z * 1024 * 8192;
  const int lr = lane & 15, lk = (lane >> 4) * 8;
  f32x4 acc[4][4] = {};
  const int sr = t >> 1, sk = (t & 1) * 16;
  for (int k0 = 0; k0 < 1024; k0 += 32) {
    __syncthreads();
    {
      const uint4* ga = (const uint4*)(A + (size_t)(mBase + sr) * 1024 + k0 + sk);
      const uint4* gb = (const uint4*)(Bt + (size_t)(nBase + sr) * 1024 + k0 + sk);
      uint4 a0 = ga[0], a1 = ga[1];
      uint4 b0 = gb[0], b1 = gb[1];
      *(uint4*)&As[sr][sk] = a0; *(uint4*)&As[sr][sk + 8] = a1;
      *(uint4*)&Bs[sr][sk] = b0; *(uint4*)&Bs[sr][sk + 8] = b1;
    }
    __syncthreads();
    f16x8 af[4], bfr[4];
#pragma unroll
    for (int i = 0; i < 4; ++i) {
      af[i]  = *(const f16x8*)&As[wr * 64 + i * 16 + lr][lk];
      bfr[i] = *(const f16x8*)&Bs[wc * 64 + i * 16 + lr][lk];
    }
#pragma unroll
    for (int i = 0; i < 4; ++i)
#pragma unroll
      for (int j = 0; j < 4; ++j)
        acc[i][j] = __builtin_amdgcn_mfma_f32_16x16x32_f16(af[i], bfr[j], acc[i][j], 0, 0, 0);
  }
  const int cr = (lane >> 4) * 4, cc = lane & 15;
#pragma unroll
  for (int i = 0; i < 4; ++i) {
#pragma unroll
    for (int j = 0; j < 4; ++j) {
      const int m0 = mBase + wr * 64 + i * 16 + cr;
      const int n0 = nBase + wc * 64 + j * 16 + cc;
#pragma unroll
      for (int g = 0; g < 4; ++g) {
        float v = acc[i][j][g] + bias[m0 + g];
        if (MODE == 0) {
          Cb[(size_t)(m0 + g) * 8192 + n0] = f2h(v);
        } else {
          const int m = m0 + g;
          const int c = m >> 9, o = m & 511;
          const int b = n0 >> 11, s = n0 & 2047;
          Cf[(size_t)b * 2097152 + (size_t)o * 4096 + c * 2048 + s] = v;
        }
      }
    }
  }
}

// ---------------- magnitudes: Cq/Ck (channel-major f16) -> Qm/Km[(bh*2048+s)][64] f16 ----------------
__global__ __launch_bounds__(256) void mag_qk(
    const unsigned short* __restrict__ Cq, const unsigned short* __restrict__ Ck,
    unsigned short* __restrict__ Qm, unsigned short* __restrict__ Km) {
  __shared__ unsigned short tl[64][72];
  const unsigned short* C = blockIdx.z ? Ck : Cq;
  unsigned short* Out = blockIdx.z ? Km : Qm;
  const int t = threadIdx.x;
  const int sBase = blockIdx.x * 64;
  const int bh = blockIdx.y, b = bh >> 3, h = bh & 7;
  const int d = t >> 2, sc = (t & 3) * 16;
  const unsigned short* pr = C + (size_t)(h * 64 + d) * 8192 + b * 2048 + sBase + sc;
  const unsigned short* pi = pr + (size_t)512 * 8192;
  unsigned short rb[16], ib[16];
  *(uint4*)&rb[0] = *(const uint4*)pr;  *(uint4*)&rb[8] = *(const uint4*)(pr + 8);
  *(uint4*)&ib[0] = *(const uint4*)pi;  *(uint4*)&ib[8] = *(const uint4*)(pi + 8);
#pragma unroll
  for (int j = 0; j < 16; ++j) {
    float fr = h2f(rb[j]), fi = h2f(ib[j]);
    tl[sc + j][d] = f2h(sqrtf(fr * fr + fi * fi + 1e-8f));
  }
  __syncthreads();
  const int s = t >> 2, dc = (t & 3) * 16;
  unsigned short* dst = Out + ((size_t)bh * 2048 + sBase + s) * 64 + dc;
  *(uint4*)dst = *(const uint4*)&tl[s][dc];
  *(uint4*)(dst + 8) = *(const uint4*)&tl[s][dc + 8];
}

// ---------------- flash attention: per (b,h, 64-query tile); writes OutT[(b*2048+s)][(c*512+h*64+d)] ----------------
__global__ __launch_bounds__(256) void attn(
    const unsigned short* __restrict__ Qm, const unsigned short* __restrict__ Km,
    const unsigned short* __restrict__ Cv, unsigned short* __restrict__ OutT) {
  __shared__ unsigned short Ks[64][72];
  __shared__ unsigned short Vrs[64][72];
  __shared__ unsigned short Vis[64][72];
  __shared__ unsigned short Ps[64][72];
  const int t = threadIdx.x, wave = t >> 6, lane = t & 63;
  const int bh = blockIdx.y, b = bh >> 3, h = bh & 7;
  const int qBase = blockIdx.x * 64;
  const int lr = lane & 15, lk = (lane >> 4) * 8;
  f16x8 qf0, qf1;
  {
    const unsigned short* qp = Qm + ((size_t)bh * 2048 + qBase + wave * 16 + lr) * 64 + lk;
    qf0 = *(const f16x8*)qp;
    qf1 = *(const f16x8*)(qp + 32);
  }
  f32x4 Or[4] = {}, Oi[4] = {};
  float mrow[4] = {-1e30f, -1e30f, -1e30f, -1e30f};
  float lrow[4] = {0.f, 0.f, 0.f, 0.f};
  const int sr = t >> 2, sc16 = (t & 3) * 16;
  const unsigned short* kmBase = Km + (size_t)bh * 2048 * 64;
  const unsigned short* vrBase = Cv + (size_t)(h * 64 + sr) * 8192 + b * 2048;
  for (int t0 = 0; t0 < 2048; t0 += 64) {
    __syncthreads();
    {
      const unsigned short* kp = kmBase + (size_t)(t0 + sr) * 64 + sc16;
      uint4 k0 = *(const uint4*)kp, k1 = *(const uint4*)(kp + 8);
      const unsigned short* vrp = vrBase + t0 + sc16;
      uint4 v0 = *(const uint4*)vrp, v1 = *(const uint4*)(vrp + 8);
      const unsigned short* vip = vrp + (size_t)512 * 8192;
      uint4 w0 = *(const uint4*)vip, w1 = *(const uint4*)(vip + 8);
      *(uint4*)&Ks[sr][sc16] = k0;  *(uint4*)&Ks[sr][sc16 + 8] = k1;
      *(uint4*)&Vrs[sr][sc16] = v0; *(uint4*)&Vrs[sr][sc16 + 8] = v1;
      *(uint4*)&Vis[sr][sc16] = w0; *(uint4*)&Vis[sr][sc16 + 8] = w1;
    }
    __syncthreads();
    // QK^T: 64 q-rows (16 per wave) x 64 t-cols, K=DK=64
    f32x4 scf[4] = {};
#pragma unroll
    for (int j = 0; j < 4; ++j) {
      f16x8 kf0 = *(const f16x8*)&Ks[j * 16 + lr][lk];
      f16x8 kf1 = *(const f16x8*)&Ks[j * 16 + lr][32 + lk];
      scf[j] = __builtin_amdgcn_mfma_f32_16x16x32_f16(qf0, kf0, scf[j], 0, 0, 0);
      scf[j] = __builtin_amdgcn_mfma_f32_16x16x32_f16(qf1, kf1, scf[j], 0, 0, 0);
    }
#pragma unroll
    for (int j = 0; j < 4; ++j) scf[j] *= 0.125f;  // 1/sqrt(DK)
    // online softmax: rows live on reg index, cols across the 16-lane group
    float al[4];
#pragma unroll
    for (int r = 0; r < 4; ++r) {
      float v = fmaxf(fmaxf(scf[0][r], scf[1][r]), fmaxf(scf[2][r], scf[3][r]));
#pragma unroll
      for (int off = 1; off < 16; off <<= 1) v = fmaxf(v, __shfl_xor(v, off, 64));
      float mnew = fmaxf(mrow[r], v);
      al[r] = __expf(mrow[r] - mnew);
      mrow[r] = mnew;
    }
    float psum[4] = {0.f, 0.f, 0.f, 0.f};
    const int prow = wave * 16 + (lane >> 4) * 4;
#pragma unroll
    for (int j = 0; j < 4; ++j) {
#pragma unroll
      for (int r = 0; r < 4; ++r) {
        float p = __expf(scf[j][r] - mrow[r]);
        unsigned short pb = f2h(p);
        psum[r] += h2f(pb);
        Ps[prow + r][j * 16 + (lane & 15)] = pb;
      }
    }
#pragma unroll
    for (int r = 0; r < 4; ++r) {
      float v = psum[r];
#pragma unroll
      for (int off = 1; off < 16; off <<= 1) v += __shfl_xor(v, off, 64);
      lrow[r] = lrow[r] * al[r] + v;
#pragma unroll
      for (int j = 0; j < 4; ++j) { Or[j][r] *= al[r]; Oi[j][r] *= al[r]; }
    }
    // PV: out[s][d] += P[s][t] * V[d][t] for real & imag (K = t = 64)
#pragma unroll
    for (int kk = 0; kk < 2; ++kk) {
      f16x8 pf = *(const f16x8*)&Ps[wave * 16 + lr][kk * 32 + lk];
#pragma unroll
      for (int j = 0; j < 4; ++j) {
        f16x8 vfr = *(const f16x8*)&Vrs[j * 16 + lr][kk * 32 + lk];
        f16x8 vfi = *(const f16x8*)&Vis[j * 16 + lr][kk * 32 + lk];
        Or[j] = __builtin_amdgcn_mfma_f32_16x16x32_f16(pf, vfr, Or[j], 0, 0, 0);
        Oi[j] = __builtin_amdgcn_mfma_f32_16x16x32_f16(pf, vfi, Oi[j], 0, 0, 0);
      }
    }
  }
#pragma unroll
  for (int r = 0; r < 4; ++r) {
    float inv = 1.0f / lrow[r];
    const int srow = qBase + wave * 16 + (lane >> 4) * 4 + r;
    unsigned short* orow = OutT + ((size_t)b * 2048 + srow) * 1024 + h * 64;
#pragma unroll
    for (int j = 0; j < 4; ++j) {
      const int dcol = j * 16 + (lane & 15);
      orow[dcol] = f2h(Or[j][r] * inv);
      orow[512 + dcol] = f2h(Oi[j][r] * inv);
    }
  }
}

extern "C" void kernel_launch(void* const* d_in, const int* in_sizes, int n_in,
                              void* d_out, int out_size, void* d_ws, size_t ws_size,
                              hipStream_t stream) {
  (void)in_sizes; (void)n_in; (void)out_size; (void)ws_size;
  const float* x = (const float*)d_in[0];

  // workspace layout (bytes): XT 16.78M | W2 8.39M | bias2 16K | Cqkv 50.33M  => ~75.5 MB
  unsigned short* XT = (unsigned short*)d_ws;
  unsigned short* W2 = XT + (size_t)8192 * 1024;
  float* bias2 = (float*)(W2 + (size_t)4 * 1024 * 1024);
  unsigned short* Cqkv = (unsigned short*)(bias2 + 4096);
  // Qm/Km live in d_out (dead before final GEMM overwrites d_out)
  unsigned short* Qm = (unsigned short*)d_out;
  unsigned short* Km = Qm + (size_t)4 * 8 * 2048 * 64;
  // OutT reuses Cq slab (dead after mag_qk)
  unsigned short* OutT = Cqkv;

  for (int s = 0; s < 4; ++s) {
    pack_w<<<4096, 256, 0, stream>>>(
        (const float*)d_in[1 + 4 * s], (const float*)d_in[2 + 4 * s],
        (const float*)d_in[3 + 4 * s], (const float*)d_in[4 + 4 * s],
        W2 + (size_t)s * 1024 * 1024, bias2 + s * 1024);
  }
  pack_x<<<dim3(32, 8, 8), 256, 0, stream>>>(x, XT);
  gemm_bt<0><<<dim3(64, 8, 3), 256, 0, stream>>>(W2, XT, bias2, Cqkv, nullptr);
  mag_qk<<<dim3(32, 32, 2), 256, 0, stream>>>(Cqkv, Cqkv + (size_t)1024 * 8192, Qm, Km);
  attn<<<dim3(32, 32), 256, 0, stream>>>(Qm, Km, Cqkv + (size_t)2 * 1024 * 8192, OutT);
  gemm_bt<1><<<dim3(64, 8, 1), 256, 0, stream>>>(
      W2 + (size_t)3 * 1024 * 1024, OutT, bias2 + 3 * 1024, nullptr, (float*)d_out);
}

// Round 3
// 296.864 us; speedup vs baseline: 1.0452x; 1.0452x over previous
//
#include <hip/hip_runtime.h>
#include <math.h>
#include <stdint.h>

typedef __attribute__((ext_vector_type(8))) _Float16 f16x8;
typedef __attribute__((ext_vector_type(4))) float f32x4;

static __device__ __forceinline__ unsigned short f2h(float f) {
  union { _Float16 h; unsigned short u; } v; v.h = (_Float16)f;
  return v.u;
}
static __device__ __forceinline__ float h2f(unsigned short u) {
  union { unsigned short u; _Float16 h; } v; v.u = u;
  return (float)v.h;
}

#define GLOAD_LDS16(g, l) __builtin_amdgcn_global_load_lds( \
    (const __attribute__((address_space(1))) void*)(g),     \
    (__attribute__((address_space(3))) void*)(l), 16, 0, 0)

// ---------------- pack weights: W2 = [[Wr,-Wi],[Wi,Wr]] (1024x1024 f16), bias2 = br∓bi ----------------
__global__ __launch_bounds__(256) void pack_w(
    const float* __restrict__ Wr, const float* __restrict__ Wi,
    const float* __restrict__ br, const float* __restrict__ bi,
    unsigned short* __restrict__ W2, float* __restrict__ bias2) {
  int idx = blockIdx.x * 256 + threadIdx.x;
  int m = idx >> 10, k = idx & 1023;
  int o = m & 511, d = k & 511;
  float v;
  if (m < 512) v = (k < 512) ? Wr[o * 512 + d] : -Wi[o * 512 + d];
  else         v = (k < 512) ? Wi[o * 512 + d] :  Wr[o * 512 + d];
  W2[idx] = f2h(v);
  if (idx < 1024) {
    int oo = idx & 511;
    bias2[idx] = (idx < 512) ? (br[oo] - bi[oo]) : (br[oo] + bi[oo]);
  }
}

// ---------------- pack x: (B,D,2,S) f32 -> XT[(b*2048+s)][(c*512+d)] f16 (B^T layout) ----------------
__global__ __launch_bounds__(256) void pack_x(
    const float* __restrict__ x, unsigned short* __restrict__ XT) {
  __shared__ unsigned short tl[64][72];
  const int t = threadIdx.x;
  const int sBase = blockIdx.x * 64, dBase = blockIdx.y * 64;
  const int b = blockIdx.z >> 1, c = blockIdx.z & 1;
  const int r = t >> 2, cb = (t & 3) * 16;
  const float* src = x + (((size_t)(b * 512 + dBase + r) * 2 + c) * 2048 + sBase + cb);
#pragma unroll
  for (int j = 0; j < 16; j += 4) {
    float4 v = *(const float4*)(src + j);
    tl[cb + j + 0][r] = f2h(v.x);
    tl[cb + j + 1][r] = f2h(v.y);
    tl[cb + j + 2][r] = f2h(v.z);
    tl[cb + j + 3][r] = f2h(v.w);
  }
  __syncthreads();
  const int s = t >> 2, dc = (t & 3) * 16;
  unsigned short* dst = XT + ((size_t)(b * 2048 + sBase + s)) * 1024 + c * 512 + dBase + dc;
  *(uint4*)dst = *(const uint4*)&tl[s][dc];
  *(uint4*)(dst + 8) = *(const uint4*)&tl[s][dc + 8];
}

// ---------------- GEMM: C[1024][8192] = A(1024x1024) * Bt(8192x1024)^T, f16 in, fp32 acc ----------------
// global_load_lds (width 16) staging into linear LDS [128][32].
template <int MODE>
__global__ __launch_bounds__(256) void gemm_bt(
    const unsigned short* __restrict__ A, const unsigned short* __restrict__ Bt,
    const float* __restrict__ bias, unsigned short* __restrict__ Cb,
    float* __restrict__ Cf) {
  __shared__ unsigned short As[128 * 32];
  __shared__ unsigned short Bs[128 * 32];
  const int t = threadIdx.x;
  const int wave = t >> 6, lane = t & 63;
  const int wr = wave >> 1, wc = wave & 1;
  const int mBase = blockIdx.y * 128, nBase = blockIdx.x * 128;
  const int z = blockIdx.z;
  A += (size_t)z * 1024 * 1024;
  bias += z * 1024;
  if (MODE == 0) Cb += (size_t)z * 1024 * 8192;
  const int lr = lane & 15, lk = (lane >> 4) * 8;
  f32x4 acc[4][4] = {};
  // staging geometry: wave w stages rows [w*32, w*32+32) of each tile, 2 issues of 16 rows
  const int grow = wave * 32 + (lane >> 2);
  const int gcol = (lane & 3) * 8;
  const unsigned short* ga = A + (size_t)(mBase + grow) * 1024 + gcol;
  const unsigned short* gb = Bt + (size_t)(nBase + grow) * 1024 + gcol;
  unsigned short* lA = &As[wave * 1024];
  unsigned short* lB = &Bs[wave * 1024];
  for (int k0 = 0; k0 < 1024; k0 += 32) {
    __syncthreads();
    GLOAD_LDS16(ga + k0, lA);
    GLOAD_LDS16(ga + 16 * 1024 + k0, lA + 512);
    GLOAD_LDS16(gb + k0, lB);
    GLOAD_LDS16(gb + 16 * 1024 + k0, lB + 512);
    __syncthreads();
    f16x8 af[4], bfr[4];
#pragma unroll
    for (int i = 0; i < 4; ++i) {
      af[i]  = *(const f16x8*)&As[(wr * 64 + i * 16 + lr) * 32 + lk];
      bfr[i] = *(const f16x8*)&Bs[(wc * 64 + i * 16 + lr) * 32 + lk];
    }
#pragma unroll
    for (int i = 0; i < 4; ++i)
#pragma unroll
      for (int j = 0; j < 4; ++j)
        acc[i][j] = __builtin_amdgcn_mfma_f32_16x16x32_f16(af[i], bfr[j], acc[i][j], 0, 0, 0);
  }
  const int cr = (lane >> 4) * 4, cc = lane & 15;
#pragma unroll
  for (int i = 0; i < 4; ++i) {
#pragma unroll
    for (int j = 0; j < 4; ++j) {
      const int m0 = mBase + wr * 64 + i * 16 + cr;
      const int n0 = nBase + wc * 64 + j * 16 + cc;
#pragma unroll
      for (int g = 0; g < 4; ++g) {
        float v = acc[i][j][g] + bias[m0 + g];
        if (MODE == 0) {
          Cb[(size_t)(m0 + g) * 8192 + n0] = f2h(v);
        } else {
          const int m = m0 + g;
          const int c = m >> 9, o = m & 511;
          const int b = n0 >> 11, s = n0 & 2047;
          Cf[(size_t)b * 2097152 + (size_t)o * 4096 + c * 2048 + s] = v;
        }
      }
    }
  }
}

// ---------------- magnitudes: Cq/Ck (channel-major f16) -> Qm/Km[(bh*2048+s)][64] f16 ----------------
__global__ __launch_bounds__(256) void mag_qk(
    const unsigned short* __restrict__ Cq, const unsigned short* __restrict__ Ck,
    unsigned short* __restrict__ Qm, unsigned short* __restrict__ Km) {
  __shared__ unsigned short tl[64][72];
  const unsigned short* C = blockIdx.z ? Ck : Cq;
  unsigned short* Out = blockIdx.z ? Km : Qm;
  const int t = threadIdx.x;
  const int sBase = blockIdx.x * 64;
  const int bh = blockIdx.y, b = bh >> 3, h = bh & 7;
  const int d = t >> 2, sc = (t & 3) * 16;
  const unsigned short* pr = C + (size_t)(h * 64 + d) * 8192 + b * 2048 + sBase + sc;
  const unsigned short* pi = pr + (size_t)512 * 8192;
  unsigned short rb[16], ib[16];
  *(uint4*)&rb[0] = *(const uint4*)pr;  *(uint4*)&rb[8] = *(const uint4*)(pr + 8);
  *(uint4*)&ib[0] = *(const uint4*)pi;  *(uint4*)&ib[8] = *(const uint4*)(pi + 8);
#pragma unroll
  for (int j = 0; j < 16; ++j) {
    float fr = h2f(rb[j]), fi = h2f(ib[j]);
    tl[sc + j][d] = f2h(sqrtf(fr * fr + fi * fi + 1e-8f));
  }
  __syncthreads();
  const int s = t >> 2, dc = (t & 3) * 16;
  unsigned short* dst = Out + ((size_t)bh * 2048 + sBase + s) * 64 + dc;
  *(uint4*)dst = *(const uint4*)&tl[s][dc];
  *(uint4*)(dst + 8) = *(const uint4*)&tl[s][dc + 8];
}

// ---------------- flash attention: QBLK=128 (4 waves x 32 q-rows), KVBLK=64 ----------------
// P stored in XOR-swizzled [128][64] LDS: col ^= ((row>>2)&3)<<4  (conflict-free u16 writes)
#define PSWZ(row, col) ((size_t)(row) * 64 + ((col) ^ ((((row) >> 2) & 3) << 4)))

__global__ __launch_bounds__(256) void attn(
    const unsigned short* __restrict__ Qm, const unsigned short* __restrict__ Km,
    const unsigned short* __restrict__ Cv, unsigned short* __restrict__ OutT) {
  __shared__ unsigned short Ks[64][72];
  __shared__ unsigned short Vrs[64][72];
  __shared__ unsigned short Vis[64][72];
  __shared__ unsigned short Ps[128 * 64];
  const int t = threadIdx.x, wave = t >> 6, lane = t & 63;
  const int bh = blockIdx.y, b = bh >> 3, h = bh & 7;
  const int qBase = blockIdx.x * 128;
  const int lr = lane & 15, hi4 = lane >> 4, lk = hi4 * 8;
  const float ls = 0.18033688f;  // log2(e)/sqrt(DK) = 1.4426950/8

  f16x8 qf[2][2];
#pragma unroll
  for (int fq = 0; fq < 2; ++fq) {
    const unsigned short* qp =
        Qm + ((size_t)bh * 2048 + qBase + wave * 32 + fq * 16 + lr) * 64 + lk;
    qf[fq][0] = *(const f16x8*)qp;
    qf[fq][1] = *(const f16x8*)(qp + 32);
  }
  f16x8 ones;
#pragma unroll
  for (int e = 0; e < 8; ++e) ones[e] = (_Float16)1.0f;

  f32x4 Or[2][4] = {}, Oi[2][4] = {};
  float mrow[2][4], lrow[2][4];
#pragma unroll
  for (int fq = 0; fq < 2; ++fq)
#pragma unroll
    for (int r = 0; r < 4; ++r) { mrow[fq][r] = -1e30f; lrow[fq][r] = 0.f; }

  const int srow = t >> 2, scol = (t & 3) * 16;
  const unsigned short* kmBase = Km + ((size_t)bh * 2048 + srow) * 64 + scol;
  const unsigned short* vrBase = Cv + (size_t)(h * 64 + srow) * 8192 + b * 2048 + scol;
  const unsigned short* viBase = vrBase + (size_t)512 * 8192;
  const int prowb = wave * 32;

  for (int t0 = 0; t0 < 2048; t0 += 64) {
    __syncthreads();
    {
      const uint4* kp = (const uint4*)(kmBase + (size_t)t0 * 64);
      uint4 ka = kp[0], kb = kp[1];
      const uint4* vp = (const uint4*)(vrBase + t0);
      uint4 va = vp[0], vb = vp[1];
      const uint4* wp = (const uint4*)(viBase + t0);
      uint4 wa = wp[0], wb = wp[1];
      *(uint4*)&Ks[srow][scol] = ka;  *(uint4*)&Ks[srow][scol + 8] = kb;
      *(uint4*)&Vrs[srow][scol] = va; *(uint4*)&Vrs[srow][scol + 8] = vb;
      *(uint4*)&Vis[srow][scol] = wa; *(uint4*)&Vis[srow][scol + 8] = wb;
    }
    __syncthreads();
    // QK^T: 2 q-frags x 4 k-frags, K-frags reused across both q-frags
    f32x4 scf[2][4] = {};
#pragma unroll
    for (int j = 0; j < 4; ++j) {
      f16x8 kf0 = *(const f16x8*)&Ks[j * 16 + lr][lk];
      f16x8 kf1 = *(const f16x8*)&Ks[j * 16 + lr][32 + lk];
      scf[0][j] = __builtin_amdgcn_mfma_f32_16x16x32_f16(qf[0][0], kf0, scf[0][j], 0, 0, 0);
      scf[0][j] = __builtin_amdgcn_mfma_f32_16x16x32_f16(qf[0][1], kf1, scf[0][j], 0, 0, 0);
      scf[1][j] = __builtin_amdgcn_mfma_f32_16x16x32_f16(qf[1][0], kf0, scf[1][j], 0, 0, 0);
      scf[1][j] = __builtin_amdgcn_mfma_f32_16x16x32_f16(qf[1][1], kf1, scf[1][j], 0, 0, 0);
    }
    // row max (raw units) -> log2 units; defer-max rescale
    float pmax[2][4];
    int need = 0;
#pragma unroll
    for (int fq = 0; fq < 2; ++fq)
#pragma unroll
      for (int r = 0; r < 4; ++r) {
        float v = fmaxf(fmaxf(scf[fq][0][r], scf[fq][1][r]),
                        fmaxf(scf[fq][2][r], scf[fq][3][r]));
        v = fmaxf(v, __shfl_xor(v, 1, 64));
        v = fmaxf(v, __shfl_xor(v, 2, 64));
        v = fmaxf(v, __shfl_xor(v, 4, 64));
        v = fmaxf(v, __shfl_xor(v, 8, 64));
        pmax[fq][r] = v * ls;
        need |= (pmax[fq][r] > mrow[fq][r] + 8.0f) ? 1 : 0;
      }
    if (__any(need)) {
#pragma unroll
      for (int fq = 0; fq < 2; ++fq)
#pragma unroll
        for (int r = 0; r < 4; ++r) {
          float mnew = fmaxf(mrow[fq][r], pmax[fq][r]);
          float al = exp2f(mrow[fq][r] - mnew);
          mrow[fq][r] = mnew;
          lrow[fq][r] *= al;
#pragma unroll
          for (int j = 0; j < 4; ++j) { Or[fq][j][r] *= al; Oi[fq][j][r] *= al; }
        }
    }
    // P = exp2(s*ls - m), bounded by 2^8; write to swizzled LDS
#pragma unroll
    for (int fq = 0; fq < 2; ++fq)
#pragma unroll
      for (int j = 0; j < 4; ++j)
#pragma unroll
        for (int r = 0; r < 4; ++r) {
          float p = exp2f(fmaf(scf[fq][j][r], ls, -mrow[fq][r]));
          Ps[PSWZ(prowb + fq * 16 + hi4 * 4 + r, j * 16 + lr)] = f2h(p);
        }
    // PV + row-sum via ones-MFMA (V-frags reused across both q-frags)
    f32x4 lt0 = {}, lt1 = {};
#pragma unroll
    for (int kk = 0; kk < 2; ++kk) {
      f16x8 pa0 = *(const f16x8*)&Ps[PSWZ(prowb + lr, kk * 32 + lk)];
      f16x8 pa1 = *(const f16x8*)&Ps[PSWZ(prowb + 16 + lr, kk * 32 + lk)];
      lt0 = __builtin_amdgcn_mfma_f32_16x16x32_f16(pa0, ones, lt0, 0, 0, 0);
      lt1 = __builtin_amdgcn_mfma_f32_16x16x32_f16(pa1, ones, lt1, 0, 0, 0);
#pragma unroll
      for (int j = 0; j < 4; ++j) {
        f16x8 vfr = *(const f16x8*)&Vrs[j * 16 + lr][kk * 32 + lk];
        f16x8 vfi = *(const f16x8*)&Vis[j * 16 + lr][kk * 32 + lk];
        Or[0][j] = __builtin_amdgcn_mfma_f32_16x16x32_f16(pa0, vfr, Or[0][j], 0, 0, 0);
        Oi[0][j] = __builtin_amdgcn_mfma_f32_16x16x32_f16(pa0, vfi, Oi[0][j], 0, 0, 0);
        Or[1][j] = __builtin_amdgcn_mfma_f32_16x16x32_f16(pa1, vfr, Or[1][j], 0, 0, 0);
        Oi[1][j] = __builtin_amdgcn_mfma_f32_16x16x32_f16(pa1, vfi, Oi[1][j], 0, 0, 0);
      }
    }
#pragma unroll
    for (int r = 0; r < 4; ++r) { lrow[0][r] += lt0[r]; lrow[1][r] += lt1[r]; }
  }
#pragma unroll
  for (int fq = 0; fq < 2; ++fq)
#pragma unroll
    for (int r = 0; r < 4; ++r) {
      float inv = 1.0f / lrow[fq][r];
      const int sr_ = qBase + wave * 32 + fq * 16 + hi4 * 4 + r;
      unsigned short* orow = OutT + ((size_t)b * 2048 + sr_) * 1024 + h * 64;
#pragma unroll
      for (int j = 0; j < 4; ++j) {
        const int dcol = j * 16 + lr;
        orow[dcol] = f2h(Or[fq][j][r] * inv);
        orow[512 + dcol] = f2h(Oi[fq][j][r] * inv);
      }
    }
}

extern "C" void kernel_launch(void* const* d_in, const int* in_sizes, int n_in,
                              void* d_out, int out_size, void* d_ws, size_t ws_size,
                              hipStream_t stream) {
  (void)in_sizes; (void)n_in; (void)out_size; (void)ws_size;
  const float* x = (const float*)d_in[0];

  // workspace layout: XT 16.78M | W2 8.39M | bias2 16K | Cqkv 50.33M  => ~75.5 MB
  unsigned short* XT = (unsigned short*)d_ws;
  unsigned short* W2 = XT + (size_t)8192 * 1024;
  float* bias2 = (float*)(W2 + (size_t)4 * 1024 * 1024);
  unsigned short* Cqkv = (unsigned short*)(bias2 + 4096);
  // Qm/Km live in d_out (dead before final GEMM overwrites d_out)
  unsigned short* Qm = (unsigned short*)d_out;
  unsigned short* Km = Qm + (size_t)4 * 8 * 2048 * 64;
  // OutT reuses Cq slab (dead after mag_qk)
  unsigned short* OutT = Cqkv;

  for (int s = 0; s < 4; ++s) {
    pack_w<<<4096, 256, 0, stream>>>(
        (const float*)d_in[1 + 4 * s], (const float*)d_in[2 + 4 * s],
        (const float*)d_in[3 + 4 * s], (const float*)d_in[4 + 4 * s],
        W2 + (size_t)s * 1024 * 1024, bias2 + s * 1024);
  }
  pack_x<<<dim3(32, 8, 8), 256, 0, stream>>>(x, XT);
  gemm_bt<0><<<dim3(64, 8, 3), 256, 0, stream>>>(W2, XT, bias2, Cqkv, nullptr);
  mag_qk<<<dim3(32, 32, 2), 256, 0, stream>>>(Cqkv, Cqkv + (size_t)1024 * 8192, Qm, Km);
  attn<<<dim3(16, 32), 256, 0, stream>>>(Qm, Km, Cqkv + (size_t)2 * 1024 * 8192, OutT);
  gemm_bt<1><<<dim3(64, 8, 1), 256, 0, stream>>>(
      W2 + (size_t)3 * 1024 * 1024, OutT, bias2 + 3 * 1024, nullptr, (float*)d_out);
}